// Round 24
// baseline (157.584 us; speedup 1.0000x reference)
//
#include <hip/hip_runtime.h>
#include <cstdint>
#include <cstddef>

#define I_DIM   2048
#define O_DIM   1024
#define TB      10
#define ITERS   1024          // T / TB
#define I4      512           // I_DIM / 4
#define LISTMAX 320           // max active batches/neuron (mean 187, sd 12.4)
#define LSTRIDE 336           // uint2 entries incl. 8 sentinels, even (uint4-aligned)
#define LOG2E   1.44269504088896340736f
#define LN2     0.69314718055994530942f

// Direct v_exp_f32 (2^x): single hw trans op (~1 ulp; threshold is 2.37).
#define EXP2_HW(x) __builtin_amdgcn_exp2f(x)

// ---------------------------------------------------------------------------
// Kernel A: one block per time-batch t (r16-proven form). float4 spike reads;
// o-major mask_T + toss[t].
// ---------------------------------------------------------------------------
__global__ __launch_bounds__(256)
void prep_kernel(const float* __restrict__ spk,
                 unsigned short* __restrict__ mask_T, // [O][ITERS]
                 float* __restrict__ toss) {          // [ITERS]
    const int t   = blockIdx.x;
    const int tid = threadIdx.x;
    const float4* base4 = (const float4*)(spk + (size_t)t * TB * O_DIM);
    float    s[4] = {0.f, 0.f, 0.f, 0.f};
    unsigned m[4] = {0u, 0u, 0u, 0u};
#pragma unroll
    for (int i = 0; i < TB; ++i) {
        float4 v = base4[(size_t)i * (O_DIM / 4) + tid];
        s[0] += v.x; if (v.x != 0.f) m[0] |= (1u << i);
        s[1] += v.y; if (v.y != 0.f) m[1] |= (1u << i);
        s[2] += v.z; if (v.z != 0.f) m[2] |= (1u << i);
        s[3] += v.w; if (v.w != 0.f) m[3] |= (1u << i);
    }
#pragma unroll
    for (int j = 0; j < 4; ++j)
        mask_T[(size_t)(tid * 4 + j) * ITERS + t] = (unsigned short)m[j];
    __shared__ float red[256];
    red[tid] = s[0] + s[1] + s[2] + s[3];
    __syncthreads();
    for (int st = 128; st > 0; st >>= 1) {
        if (tid < st) red[tid] += red[tid + st];
        __syncthreads();
    }
    if (tid == 0) toss[t] = red[0];
}

// ---------------------------------------------------------------------------
// Kernel B (fused): blocks 0..255 = compaction (one wave per neuron) emitting
// uint2 {row0|s0<<14|rem<<18|tos<<28, -inv}; 8 zero-sentinels appended.
// Blocks 256..259 = bias with h_t precompute + r16 memory pattern + hw exp2.
// ---------------------------------------------------------------------------
__global__ __launch_bounds__(256)
void compact_bias_kernel(const unsigned short* __restrict__ mask_T, // [O][ITERS]
                         const float* __restrict__ toss,
                         const float* __restrict__ Nk,
                         const float* __restrict__ b_in,
                         uint2* __restrict__ lists,   // [O][LSTRIDE]
                         int* __restrict__ counts,    // [O]
                         float* __restrict__ b_out) {
    __shared__ float s_h[ITERS];        // 4 KB (bias blocks only)
    __shared__ float red[256];          // 1 KB
    const int tid = threadIdx.x;
    if (blockIdx.x < 256) {
        // ---- compaction ----
        const int o    = blockIdx.x * 4 + (tid >> 6);
        const int lane = tid & 63;
        const unsigned short* row = mask_T + (size_t)o * ITERS;
        uint2* list = lists + (size_t)o * LSTRIDE;
        const float nk0 = Nk[o];
        int cnt = 0, tot = 0;
        for (int base = 0; base < ITERS; base += 64) {
            unsigned int m = row[base + lane];
            bool act = (m != 0u);
            int tos = __popc(m);
            int v = tos;
#pragma unroll
            for (int d = 1; d < 64; d <<= 1) {
                int y = __shfl_up(v, d);
                if (lane >= d) v += y;
            }
            const int excl = v - tos;
            unsigned long long b = __ballot(act);
            int pre = __popcll(b & ((1ull << lane) - 1ull));
            if (act && cnt + pre < LISTMAX) {
                float nk_k = nk0 + (float)(tot + excl);
                float inv  = __builtin_amdgcn_rcpf(nk_k) * LOG2E;
                unsigned s0   = (unsigned)(__ffs(m) - 1);
                unsigned row0 = (unsigned)(base + lane) * TB + s0;
                unsigned info = row0 | (s0 << 14) | ((m & (m - 1)) << 18)
                              | ((unsigned)tos << 28);
                list[cnt + pre] = make_uint2(info, __float_as_uint(-inv));
            }
            cnt += __popcll(b);
            tot += __shfl(v, 63);
        }
        if (lane < 8) {                            // 8 sentinels: ninv=0 -> no-op
            int c = cnt < LISTMAX ? cnt : LISTMAX;
            if (lane == 0) counts[o] = c;
            list[c + lane] = make_uint2(0u, 0u);
        }
    } else {
        // ---- bias: h_t precompute + r16 memory pattern ----
        float s = 0.f;
        for (int i = tid; i < O_DIM; i += 256) s += Nk[i];
        red[tid] = s;
        __syncthreads();
        for (int st = 128; st > 0; st >>= 1) {
            if (tid < st) red[tid] += red[tid + st];
            __syncthreads();
        }
        const float snk0 = red[0];
        __syncthreads();

        const int t0 = tid * 4;
        const float4 tv = ((const float4*)toss)[tid];
        red[tid] = tv.x + tv.y + tv.z + tv.w;
        __syncthreads();
        for (int d = 1; d < 256; d <<= 1) {
            float add = (tid >= d) ? red[tid - d] : 0.f;
            __syncthreads();
            red[tid] += add;
            __syncthreads();
        }
        const float base = (tid ? red[tid - 1] : 0.f) + snk0;
        s_h[t0]     = LOG2E * tv.x * __builtin_amdgcn_rcpf(base);
        s_h[t0 + 1] = LOG2E * tv.y * __builtin_amdgcn_rcpf(base + tv.x);
        s_h[t0 + 2] = LOG2E * tv.z * __builtin_amdgcn_rcpf(base + tv.x + tv.y);
        s_h[t0 + 3] = LOG2E * tv.w * __builtin_amdgcn_rcpf(base + tv.x + tv.y + tv.z);
        __syncthreads();

        const int o = (blockIdx.x - 256) * 256 + tid;
        float bs = b_in[o] * LOG2E;
        const uint4* row4 = (const uint4*)(mask_T + (size_t)o * ITERS);
        for (int blk = 0; blk < ITERS / 8; ++blk) {
            uint4 v = row4[blk];
            unsigned wds[4] = {v.x, v.y, v.z, v.w};
#pragma unroll
            for (int j = 0; j < 8; ++j) {
                unsigned m = (wds[j >> 1] >> ((j & 1) * 16)) & 0xFFFFu;
                float tos_t = (float)__popc(m);
                float h = s_h[blk * 8 + j];
                float e = EXP2_HW(-bs);
                bs = __builtin_fmaf(h * tos_t, e, bs) - h;
            }
        }
        b_out[o] = bs * LN2;
    }
}

// ---------------------------------------------------------------------------
// Kernel C: weight rows. XCD-partitioned segments (seg=bid&7), whole grid
// co-resident, depth-4/6 pipeline (r22-proven) + SECOND-SPIKE PREFETCH:
// ~12% of entries have a 2nd spike whose row was demand-loaded (full L2
// latency stall). Now its load is issued at pipeline time (2 iters ahead,
// uniform branch) and merged p+=x one iter later (latency covered). Only
// 3rd+ spikes (~0.5%) remain demand-loaded.
// ---------------------------------------------------------------------------
__global__ __launch_bounds__(256)
void stdp_main_kernel(const float* __restrict__ psp,
                      const float* __restrict__ w_in,
                      const uint2* __restrict__ lists,
                      const int* __restrict__ counts,
                      float* __restrict__ w_out) {
    const int bid  = blockIdx.x;
    const int seg  = bid & 7;
    const int wv   = __builtin_amdgcn_readfirstlane(threadIdx.x >> 6);
    const int lane = threadIdx.x & 63;
    const int o    = ((bid >> 3) << 2) | wv;
    const int lane4 = seg * 64 + lane;             // float4 index within the row

    const float4* __restrict__ psp4 = (const float4*)psp + lane4;
    float4 w0 = ((const float4*)w_in)[(size_t)o * I4 + lane4];
    float4 n = make_float4(w0.x * -LOG2E, w0.y * -LOG2E,
                           w0.z * -LOG2E, w0.w * -LOG2E);

    const uint2* lp  = lists + (size_t)o * LSTRIDE; // uniform base
    const uint4* lp4 = (const uint4*)lp;            // entry pairs (16B aligned)
    const int count = counts[o];                    // uniform -> s_load

    auto rowof = [&](unsigned ex) -> float4 {       // first-spike row
        return psp4[(size_t)(ex & 0x3FFFu) << 9];
    };
    auto rowof2 = [&](unsigned ex, unsigned rem) -> float4 {  // second-spike row
        unsigned t10 = (ex & 0x3FFFu) - ((ex >> 14) & 0xFu);
        unsigned r1  = t10 + (unsigned)(__ffs(rem) - 1);
        return psp4[(size_t)r1 << 9];
    };

    if (count > 0) {
        uint4 A = lp4[0];                          // entries 0,1
        uint4 B = lp4[1];                          // entries 2,3
        uint4 C = lp4[2];                          // entries 4,5
        float4 p0 = rowof(A.x), p1 = rowof(A.z);
        float4 p2 = rowof(B.x), p3 = rowof(B.z);
        float4 x2, x3;
        {   // second-spike loads for entries 0..3; merge pair A now (startup)
            unsigned rA0 = (A.x >> 18) & 0x3FFu, rA1 = (A.z >> 18) & 0x3FFu;
            unsigned rB0 = (B.x >> 18) & 0x3FFu, rB1 = (B.z >> 18) & 0x3FFu;
            float4 x0, x1;
            if (rA0) x0 = rowof2(A.x, rA0);
            if (rA1) x1 = rowof2(A.z, rA1);
            if (rB0) x2 = rowof2(B.x, rB0);
            if (rB1) x3 = rowof2(B.z, rB1);
            if (rA0) { p0.x += x0.x; p0.y += x0.y; p0.z += x0.z; p0.w += x0.w; }
            if (rA1) { p1.x += x1.x; p1.y += x1.y; p1.z += x1.z; p1.w += x1.w; }
        }

        for (int k = 0; k < count; k += 2) {
            const uint4 D = lp4[(k >> 1) + 3];             // entries k+6,k+7
            const float4 p4 = rowof(C.x), p5 = rowof(C.z); // rows k+4,k+5
            float4 x4, x5;
            const unsigned rC0 = (C.x >> 18) & 0x3FFu;
            const unsigned rC1 = (C.z >> 18) & 0x3FFu;
            if (rC0) x4 = rowof2(C.x, rC0);
            if (rC1) x5 = rowof2(C.z, rC1);

            // merge pair B (entries k+2,k+3): loads issued last iter, covered
            const unsigned rB0 = (B.x >> 18) & 0x3FFu;
            const unsigned rB1 = (B.z >> 18) & 0x3FFu;
            if (rB0) { p2.x += x2.x; p2.y += x2.y; p2.z += x2.z; p2.w += x2.w; }
            if (rB1) { p3.x += x3.x; p3.y += x3.y; p3.z += x3.z; p3.w += x3.w; }

            // ---- consume entry k (A.x, p0 already includes 2nd spike) ----
            {
                float4 c = p0;
                unsigned rA0 = (A.x >> 18) & 0x3FFu;
                unsigned rem2 = rA0 & (rA0 - 1);           // 3rd+ spikes, ~0.5%
                if (rem2) {
                    unsigned t10 = (A.x & 0x3FFFu) - ((A.x >> 14) & 0xFu);
                    do {
                        int sbit = __ffs(rem2) - 1;
                        rem2 &= rem2 - 1;
                        const float4 q = psp4[(size_t)(t10 + sbit) << 9];
                        c.x += q.x; c.y += q.y; c.z += q.z; c.w += q.w;
                    } while (rem2);
                }
                const float ninv = __uint_as_float(A.y);
                const float tosf = (float)(A.x >> 28);
                float t, s;
                t = EXP2_HW(n.x); s = __builtin_fmaf(c.x, t, -tosf); n.x = __builtin_fmaf(ninv, s, n.x);
                t = EXP2_HW(n.y); s = __builtin_fmaf(c.y, t, -tosf); n.y = __builtin_fmaf(ninv, s, n.y);
                t = EXP2_HW(n.z); s = __builtin_fmaf(c.z, t, -tosf); n.z = __builtin_fmaf(ninv, s, n.z);
                t = EXP2_HW(n.w); s = __builtin_fmaf(c.w, t, -tosf); n.w = __builtin_fmaf(ninv, s, n.w);
            }
            // ---- consume entry k+1 (A.z, p1) ----
            {
                float4 c = p1;
                unsigned rA1 = (A.z >> 18) & 0x3FFu;
                unsigned rem2 = rA1 & (rA1 - 1);
                if (rem2) {
                    unsigned t10 = (A.z & 0x3FFFu) - ((A.z >> 14) & 0xFu);
                    do {
                        int sbit = __ffs(rem2) - 1;
                        rem2 &= rem2 - 1;
                        const float4 q = psp4[(size_t)(t10 + sbit) << 9];
                        c.x += q.x; c.y += q.y; c.z += q.z; c.w += q.w;
                    } while (rem2);
                }
                const float ninv = __uint_as_float(A.w);
                const float tosf = (float)(A.z >> 28);
                float t, s;
                t = EXP2_HW(n.x); s = __builtin_fmaf(c.x, t, -tosf); n.x = __builtin_fmaf(ninv, s, n.x);
                t = EXP2_HW(n.y); s = __builtin_fmaf(c.y, t, -tosf); n.y = __builtin_fmaf(ninv, s, n.y);
                t = EXP2_HW(n.z); s = __builtin_fmaf(c.z, t, -tosf); n.z = __builtin_fmaf(ninv, s, n.z);
                t = EXP2_HW(n.w); s = __builtin_fmaf(c.w, t, -tosf); n.w = __builtin_fmaf(ninv, s, n.w);
            }

            A = B; B = C; C = D;
            p0 = p2; p1 = p3; p2 = p4; p3 = p5;
            x2 = x4; x3 = x5;
        }
    }

    float4 ov = make_float4(n.x * -LN2, n.y * -LN2, n.z * -LN2, n.w * -LN2);
    ((float4*)w_out)[(size_t)o * I4 + lane4] = ov;
}

// ---------------------------------------------------------------------------
extern "C" void kernel_launch(void* const* d_in, const int* in_sizes, int n_in,
                              void* d_out, int out_size, void* d_ws, size_t ws_size,
                              hipStream_t stream) {
    const float* psp = (const float*)d_in[0];   // (T, I)
    const float* spk = (const float*)d_in[1];   // (T, O)
    const float* w   = (const float*)d_in[2];   // (O, I)
    const float* b   = (const float*)d_in[3];   // (O,)
    const float* Nk  = (const float*)d_in[4];   // (O, 1)

    float* w_out = (float*)d_out;
    float* b_out = (float*)d_out + (size_t)O_DIM * I_DIM;

    char* ws = (char*)d_ws;
    unsigned short* mask_T = (unsigned short*)ws;                              // 2 MB
    uint2*          lists  = (uint2*)(ws + (size_t)O_DIM * ITERS * 2);         // 2.75 MB
    int*            counts = (int*)(ws + (size_t)O_DIM * ITERS * 2
                                       + (size_t)O_DIM * LSTRIDE * 8);         // 4 KB
    float*          toss   = (float*)(counts + O_DIM);                         // 4 KB

    prep_kernel<<<ITERS, 256, 0, stream>>>(spk, mask_T, toss);
    compact_bias_kernel<<<260, 256, 0, stream>>>(mask_T, toss, Nk, b,
                                                 lists, counts, b_out);
    stdp_main_kernel<<<O_DIM / 4 * 8, 256, 0, stream>>>(psp, w, lists, counts, w_out);
}

// Round 25
// 145.706 us; speedup vs baseline: 1.0815x; 1.0815x over previous
//
#include <hip/hip_runtime.h>
#include <cstdint>
#include <cstddef>

#define I_DIM   2048
#define O_DIM   1024
#define TB      10
#define ITERS   1024          // T / TB
#define I4      512           // I_DIM / 4
#define LISTMAX 320           // max spike-entries/neuron (mean ~205, sd ~14 -> 8 sigma)
#define LSTRIDE 336           // uint2 entries incl. 8 sentinels, even (uint4-aligned)
#define ACCUMF  0x8000u       // bit 15: accumulate-only entry (ninv=0)
#define LOG2E   1.44269504088896340736f
#define LN2     0.69314718055994530942f

// Direct v_exp_f32 (2^x): single hw trans op (~1 ulp; threshold is 2.37).
#define EXP2_HW(x) __builtin_amdgcn_exp2f(x)

// ---------------------------------------------------------------------------
// Kernel A: one block per time-batch t (r16-proven form). float4 spike reads;
// o-major mask_T + toss[t].
// ---------------------------------------------------------------------------
__global__ __launch_bounds__(256)
void prep_kernel(const float* __restrict__ spk,
                 unsigned short* __restrict__ mask_T, // [O][ITERS]
                 float* __restrict__ toss) {          // [ITERS]
    const int t   = blockIdx.x;
    const int tid = threadIdx.x;
    const float4* base4 = (const float4*)(spk + (size_t)t * TB * O_DIM);
    float    s[4] = {0.f, 0.f, 0.f, 0.f};
    unsigned m[4] = {0u, 0u, 0u, 0u};
#pragma unroll
    for (int i = 0; i < TB; ++i) {
        float4 v = base4[(size_t)i * (O_DIM / 4) + tid];
        s[0] += v.x; if (v.x != 0.f) m[0] |= (1u << i);
        s[1] += v.y; if (v.y != 0.f) m[1] |= (1u << i);
        s[2] += v.z; if (v.z != 0.f) m[2] |= (1u << i);
        s[3] += v.w; if (v.w != 0.f) m[3] |= (1u << i);
    }
#pragma unroll
    for (int j = 0; j < 4; ++j)
        mask_T[(size_t)(tid * 4 + j) * ITERS + t] = (unsigned short)m[j];
    __shared__ float red[256];
    red[tid] = s[0] + s[1] + s[2] + s[3];
    __syncthreads();
    for (int st = 128; st > 0; st >>= 1) {
        if (tid < st) red[tid] += red[tid + st];
        __syncthreads();
    }
    if (tid == 0) toss[t] = red[0];
}

// ---------------------------------------------------------------------------
// Kernel B (fused): blocks 0..255 = compaction, ONE ENTRY PER SPIKE:
// a k-spike batch emits k-1 ACCUM entries {row|ACCUMF, 0} then one COMMIT
// {row|tos<<28, -inv}. Entry count == spike count; position = spike prefix
// sum (tot + excl + j). 8 zero sentinels (COMMIT no-ops). Blocks 256..259 =
// bias with h_t precompute + r16 memory pattern + hw exp2 (unchanged).
// ---------------------------------------------------------------------------
__global__ __launch_bounds__(256)
void compact_bias_kernel(const unsigned short* __restrict__ mask_T, // [O][ITERS]
                         const float* __restrict__ toss,
                         const float* __restrict__ Nk,
                         const float* __restrict__ b_in,
                         uint2* __restrict__ lists,   // [O][LSTRIDE]
                         int* __restrict__ counts,    // [O]
                         float* __restrict__ b_out) {
    __shared__ float s_h[ITERS];        // 4 KB (bias blocks only)
    __shared__ float red[256];          // 1 KB
    const int tid = threadIdx.x;
    if (blockIdx.x < 256) {
        // ---- compaction (spike entries) ----
        const int o    = blockIdx.x * 4 + (tid >> 6);
        const int lane = tid & 63;
        const unsigned short* row = mask_T + (size_t)o * ITERS;
        uint2* list = lists + (size_t)o * LSTRIDE;
        const float nk0 = Nk[o];
        int tot = 0;                               // cumulative spikes (=entries)
        for (int base = 0; base < ITERS; base += 64) {
            unsigned int m = row[base + lane];
            int tos = __popc(m);
            int v = tos;                           // inclusive shfl scan
#pragma unroll
            for (int d = 1; d < 64; d <<= 1) {
                int y = __shfl_up(v, d);
                if (lane >= d) v += y;
            }
            const int excl = v - tos;
            if (m) {
                float nk_k = nk0 + (float)(tot + excl);  // nk BEFORE this batch
                float inv  = __builtin_amdgcn_rcpf(nk_k) * LOG2E;
                unsigned t10 = (unsigned)(base + lane) * TB;
                int pos = tot + excl;
                unsigned mm = m;
                while (mm) {
                    int s = __ffs(mm) - 1;
                    mm &= mm - 1;
                    if (pos < LISTMAX) {
                        if (mm)                    // more spikes follow: ACCUM
                            list[pos] = make_uint2((t10 + s) | ACCUMF, 0u);
                        else                       // last spike: COMMIT
                            list[pos] = make_uint2((t10 + s) | ((unsigned)tos << 28),
                                                   __float_as_uint(-inv));
                    }
                    ++pos;
                }
            }
            tot += __shfl(v, 63);
        }
        if (lane < 8) {                            // 8 sentinels: COMMIT no-ops
            int c = tot < LISTMAX ? tot : LISTMAX;
            if (lane == 0) counts[o] = c;
            list[c + lane] = make_uint2(0u, 0u);
        }
    } else {
        // ---- bias: h_t precompute + r16 memory pattern ----
        float s = 0.f;
        for (int i = tid; i < O_DIM; i += 256) s += Nk[i];
        red[tid] = s;
        __syncthreads();
        for (int st = 128; st > 0; st >>= 1) {
            if (tid < st) red[tid] += red[tid + st];
            __syncthreads();
        }
        const float snk0 = red[0];
        __syncthreads();

        const int t0 = tid * 4;
        const float4 tv = ((const float4*)toss)[tid];
        red[tid] = tv.x + tv.y + tv.z + tv.w;
        __syncthreads();
        for (int d = 1; d < 256; d <<= 1) {
            float add = (tid >= d) ? red[tid - d] : 0.f;
            __syncthreads();
            red[tid] += add;
            __syncthreads();
        }
        const float base = (tid ? red[tid - 1] : 0.f) + snk0;
        s_h[t0]     = LOG2E * tv.x * __builtin_amdgcn_rcpf(base);
        s_h[t0 + 1] = LOG2E * tv.y * __builtin_amdgcn_rcpf(base + tv.x);
        s_h[t0 + 2] = LOG2E * tv.z * __builtin_amdgcn_rcpf(base + tv.x + tv.y);
        s_h[t0 + 3] = LOG2E * tv.w * __builtin_amdgcn_rcpf(base + tv.x + tv.y + tv.z);
        __syncthreads();

        const int o = (blockIdx.x - 256) * 256 + tid;
        float bs = b_in[o] * LOG2E;
        const uint4* row4 = (const uint4*)(mask_T + (size_t)o * ITERS);
        for (int blk = 0; blk < ITERS / 8; ++blk) {
            uint4 v = row4[blk];
            unsigned wds[4] = {v.x, v.y, v.z, v.w};
#pragma unroll
            for (int j = 0; j < 8; ++j) {
                unsigned m = (wds[j >> 1] >> ((j & 1) * 16)) & 0xFFFFu;
                float tos_t = (float)__popc(m);
                float h = s_h[blk * 8 + j];
                float e = EXP2_HW(-bs);
                bs = __builtin_fmaf(h * tos_t, e, bs) - h;
            }
        }
        b_out[o] = bs * LN2;
    }
}

// ---------------------------------------------------------------------------
// Kernel C: weight rows. XCD-partitioned segments (seg=bid&7), whole grid
// co-resident, depth-4/6 pipeline (r22-proven spacing) with a FULLY UNIFORM
// body: one row load per entry, no branches, no demand loads. ACCUM entries
// fold their row into cpend (ninv=0 -> n-update is a no-op); COMMIT entries
// consume cpend + their row. Waves stay in lockstep -> L2 locality preserved
// (r23/r24 lesson: any irregular/speculative load desyncs and inflates FETCH).
// ---------------------------------------------------------------------------
__global__ __launch_bounds__(256)
void stdp_main_kernel(const float* __restrict__ psp,
                      const float* __restrict__ w_in,
                      const uint2* __restrict__ lists,
                      const int* __restrict__ counts,
                      float* __restrict__ w_out) {
    const int bid  = blockIdx.x;
    const int seg  = bid & 7;
    const int wv   = __builtin_amdgcn_readfirstlane(threadIdx.x >> 6);
    const int lane = threadIdx.x & 63;
    const int o    = ((bid >> 3) << 2) | wv;
    const int lane4 = seg * 64 + lane;             // float4 index within the row

    const float4* __restrict__ psp4 = (const float4*)psp + lane4;
    float4 w0 = ((const float4*)w_in)[(size_t)o * I4 + lane4];
    float4 n = make_float4(w0.x * -LOG2E, w0.y * -LOG2E,
                           w0.z * -LOG2E, w0.w * -LOG2E);
    float4 cpend = make_float4(0.f, 0.f, 0.f, 0.f);

    const uint2* lp  = lists + (size_t)o * LSTRIDE; // uniform base
    const uint4* lp4 = (const uint4*)lp;            // entry pairs (16B aligned)
    const int count = counts[o];                    // uniform -> s_load

    auto rowof = [&](unsigned ex) -> float4 {
        return psp4[(size_t)(ex & 0x3FFFu) << 9];
    };

    if (count > 0) {
        uint4 A = lp4[0];                          // entries 0,1
        uint4 B = lp4[1];                          // entries 2,3
        uint4 C = lp4[2];                          // entries 4,5
        float4 p0 = rowof(A.x), p1 = rowof(A.z);
        float4 p2 = rowof(B.x), p3 = rowof(B.z);

        for (int k = 0; k < count; k += 2) {
            const uint4 D = lp4[(k >> 1) + 3];             // entries k+6,k+7
            const float4 p4 = rowof(C.x), p5 = rowof(C.z); // rows k+4,k+5

            // ---- entry k (A.x/A.y, row p0) ----
            {
                float4 c = make_float4(p0.x + cpend.x, p0.y + cpend.y,
                                       p0.z + cpend.z, p0.w + cpend.w);
                const float ninv = __uint_as_float(A.y);   // 0 for ACCUM/sentinel
                const float tosf = (float)(A.x >> 28);
                float t, s;
                t = EXP2_HW(n.x); s = __builtin_fmaf(c.x, t, -tosf); n.x = __builtin_fmaf(ninv, s, n.x);
                t = EXP2_HW(n.y); s = __builtin_fmaf(c.y, t, -tosf); n.y = __builtin_fmaf(ninv, s, n.y);
                t = EXP2_HW(n.z); s = __builtin_fmaf(c.z, t, -tosf); n.z = __builtin_fmaf(ninv, s, n.z);
                t = EXP2_HW(n.w); s = __builtin_fmaf(c.w, t, -tosf); n.w = __builtin_fmaf(ninv, s, n.w);
                const bool acc = (A.x & ACCUMF) != 0u;     // uniform
                cpend.x = acc ? c.x : 0.f; cpend.y = acc ? c.y : 0.f;
                cpend.z = acc ? c.z : 0.f; cpend.w = acc ? c.w : 0.f;
            }
            // ---- entry k+1 (A.z/A.w, row p1) ----
            {
                float4 c = make_float4(p1.x + cpend.x, p1.y + cpend.y,
                                       p1.z + cpend.z, p1.w + cpend.w);
                const float ninv = __uint_as_float(A.w);
                const float tosf = (float)(A.z >> 28);
                float t, s;
                t = EXP2_HW(n.x); s = __builtin_fmaf(c.x, t, -tosf); n.x = __builtin_fmaf(ninv, s, n.x);
                t = EXP2_HW(n.y); s = __builtin_fmaf(c.y, t, -tosf); n.y = __builtin_fmaf(ninv, s, n.y);
                t = EXP2_HW(n.z); s = __builtin_fmaf(c.z, t, -tosf); n.z = __builtin_fmaf(ninv, s, n.z);
                t = EXP2_HW(n.w); s = __builtin_fmaf(c.w, t, -tosf); n.w = __builtin_fmaf(ninv, s, n.w);
                const bool acc = (A.z & ACCUMF) != 0u;
                cpend.x = acc ? c.x : 0.f; cpend.y = acc ? c.y : 0.f;
                cpend.z = acc ? c.z : 0.f; cpend.w = acc ? c.w : 0.f;
            }

            A = B; B = C; C = D;
            p0 = p2; p1 = p3; p2 = p4; p3 = p5;
        }
    }

    float4 ov = make_float4(n.x * -LN2, n.y * -LN2, n.z * -LN2, n.w * -LN2);
    ((float4*)w_out)[(size_t)o * I4 + lane4] = ov;
}

// ---------------------------------------------------------------------------
extern "C" void kernel_launch(void* const* d_in, const int* in_sizes, int n_in,
                              void* d_out, int out_size, void* d_ws, size_t ws_size,
                              hipStream_t stream) {
    const float* psp = (const float*)d_in[0];   // (T, I)
    const float* spk = (const float*)d_in[1];   // (T, O)
    const float* w   = (const float*)d_in[2];   // (O, I)
    const float* b   = (const float*)d_in[3];   // (O,)
    const float* Nk  = (const float*)d_in[4];   // (O, 1)

    float* w_out = (float*)d_out;
    float* b_out = (float*)d_out + (size_t)O_DIM * I_DIM;

    char* ws = (char*)d_ws;
    unsigned short* mask_T = (unsigned short*)ws;                              // 2 MB
    uint2*          lists  = (uint2*)(ws + (size_t)O_DIM * ITERS * 2);         // 2.75 MB
    int*            counts = (int*)(ws + (size_t)O_DIM * ITERS * 2
                                       + (size_t)O_DIM * LSTRIDE * 8);         // 4 KB
    float*          toss   = (float*)(counts + O_DIM);                         // 4 KB

    prep_kernel<<<ITERS, 256, 0, stream>>>(spk, mask_T, toss);
    compact_bias_kernel<<<260, 256, 0, stream>>>(mask_T, toss, Nk, b,
                                                 lists, counts, b_out);
    stdp_main_kernel<<<O_DIM / 4 * 8, 256, 0, stream>>>(psp, w, lists, counts, w_out);
}

// Round 28
// 129.969 us; speedup vs baseline: 1.2125x; 1.1211x over previous
//
#include <hip/hip_runtime.h>
#include <cstdint>
#include <cstddef>

#define I_DIM   2048
#define O_DIM   1024
#define TB      10
#define ITERS   1024          // T / TB
#define I4      512           // I_DIM / 4
#define LISTMAX 320           // max active batches/neuron (mean 187, sd 12.4)
#define LSTRIDE 336           // uint2 entries incl. 8 sentinels, even (uint4-aligned)
#define LOG2E   1.44269504088896340736f
#define LN2     0.69314718055994530942f

// Direct v_exp_f32 (2^x): single hw trans op (~1 ulp; threshold is 2.37).
#define EXP2_HW(x) __builtin_amdgcn_exp2f(x)

// ---------------------------------------------------------------------------
// Kernel A: one block per time-batch t (r16-proven form). float4 spike reads;
// o-major mask_T + toss[t].
// ---------------------------------------------------------------------------
__global__ __launch_bounds__(256)
void prep_kernel(const float* __restrict__ spk,
                 unsigned short* __restrict__ mask_T, // [O][ITERS]
                 float* __restrict__ toss) {          // [ITERS]
    const int t   = blockIdx.x;
    const int tid = threadIdx.x;
    const float4* base4 = (const float4*)(spk + (size_t)t * TB * O_DIM);
    float    s[4] = {0.f, 0.f, 0.f, 0.f};
    unsigned m[4] = {0u, 0u, 0u, 0u};
#pragma unroll
    for (int i = 0; i < TB; ++i) {
        float4 v = base4[(size_t)i * (O_DIM / 4) + tid];
        s[0] += v.x; if (v.x != 0.f) m[0] |= (1u << i);
        s[1] += v.y; if (v.y != 0.f) m[1] |= (1u << i);
        s[2] += v.z; if (v.z != 0.f) m[2] |= (1u << i);
        s[3] += v.w; if (v.w != 0.f) m[3] |= (1u << i);
    }
#pragma unroll
    for (int j = 0; j < 4; ++j)
        mask_T[(size_t)(tid * 4 + j) * ITERS + t] = (unsigned short)m[j];
    __shared__ float red[256];
    red[tid] = s[0] + s[1] + s[2] + s[3];
    __syncthreads();
    for (int st = 128; st > 0; st >>= 1) {
        if (tid < st) red[tid] += red[tid + st];
        __syncthreads();
    }
    if (tid == 0) toss[t] = red[0];
}

// ---------------------------------------------------------------------------
// Kernel B (fused): blocks 0..255 = compaction (one wave per neuron) emitting
// uint2 {row0|s0<<14|rem<<18|tos<<28, -inv}; 8 zero-sentinels appended.
// Blocks 256..259 = bias with h_t precompute + r16 memory pattern + hw exp2.
// ---------------------------------------------------------------------------
__global__ __launch_bounds__(256)
void compact_bias_kernel(const unsigned short* __restrict__ mask_T, // [O][ITERS]
                         const float* __restrict__ toss,
                         const float* __restrict__ Nk,
                         const float* __restrict__ b_in,
                         uint2* __restrict__ lists,   // [O][LSTRIDE]
                         int* __restrict__ counts,    // [O]
                         float* __restrict__ b_out) {
    __shared__ float s_h[ITERS];        // 4 KB (bias blocks only)
    __shared__ float red[256];          // 1 KB
    const int tid = threadIdx.x;
    if (blockIdx.x < 256) {
        // ---- compaction ----
        const int o    = blockIdx.x * 4 + (tid >> 6);
        const int lane = tid & 63;
        const unsigned short* row = mask_T + (size_t)o * ITERS;
        uint2* list = lists + (size_t)o * LSTRIDE;
        const float nk0 = Nk[o];
        int cnt = 0, tot = 0;
        for (int base = 0; base < ITERS; base += 64) {
            unsigned int m = row[base + lane];
            bool act = (m != 0u);
            int tos = __popc(m);
            int v = tos;
#pragma unroll
            for (int d = 1; d < 64; d <<= 1) {
                int y = __shfl_up(v, d);
                if (lane >= d) v += y;
            }
            const int excl = v - tos;
            unsigned long long b = __ballot(act);
            int pre = __popcll(b & ((1ull << lane) - 1ull));
            if (act && cnt + pre < LISTMAX) {
                float nk_k = nk0 + (float)(tot + excl);
                float inv  = __builtin_amdgcn_rcpf(nk_k) * LOG2E;
                unsigned s0   = (unsigned)(__ffs(m) - 1);
                unsigned row0 = (unsigned)(base + lane) * TB + s0;
                unsigned info = row0 | (s0 << 14) | ((m & (m - 1)) << 18)
                              | ((unsigned)tos << 28);
                list[cnt + pre] = make_uint2(info, __float_as_uint(-inv));
            }
            cnt += __popcll(b);
            tot += __shfl(v, 63);
        }
        if (lane < 8) {                            // 8 sentinels: ninv=0 -> no-op
            int c = cnt < LISTMAX ? cnt : LISTMAX;
            if (lane == 0) counts[o] = c;
            list[c + lane] = make_uint2(0u, 0u);
        }
    } else {
        // ---- bias: h_t precompute + r16 memory pattern ----
        float s = 0.f;
        for (int i = tid; i < O_DIM; i += 256) s += Nk[i];
        red[tid] = s;
        __syncthreads();
        for (int st = 128; st > 0; st >>= 1) {
            if (tid < st) red[tid] += red[tid + st];
            __syncthreads();
        }
        const float snk0 = red[0];
        __syncthreads();

        const int t0 = tid * 4;
        const float4 tv = ((const float4*)toss)[tid];
        red[tid] = tv.x + tv.y + tv.z + tv.w;
        __syncthreads();
        for (int d = 1; d < 256; d <<= 1) {
            float add = (tid >= d) ? red[tid - d] : 0.f;
            __syncthreads();
            red[tid] += add;
            __syncthreads();
        }
        const float base = (tid ? red[tid - 1] : 0.f) + snk0;
        s_h[t0]     = LOG2E * tv.x * __builtin_amdgcn_rcpf(base);
        s_h[t0 + 1] = LOG2E * tv.y * __builtin_amdgcn_rcpf(base + tv.x);
        s_h[t0 + 2] = LOG2E * tv.z * __builtin_amdgcn_rcpf(base + tv.x + tv.y);
        s_h[t0 + 3] = LOG2E * tv.w * __builtin_amdgcn_rcpf(base + tv.x + tv.y + tv.z);
        __syncthreads();

        const int o = (blockIdx.x - 256) * 256 + tid;
        float bs = b_in[o] * LOG2E;
        const uint4* row4 = (const uint4*)(mask_T + (size_t)o * ITERS);
        for (int blk = 0; blk < ITERS / 8; ++blk) {
            uint4 v = row4[blk];
            unsigned wds[4] = {v.x, v.y, v.z, v.w};
#pragma unroll
            for (int j = 0; j < 8; ++j) {
                unsigned m = (wds[j >> 1] >> ((j & 1) * 16)) & 0xFFFFu;
                float tos_t = (float)__popc(m);
                float h = s_h[blk * 8 + j];
                float e = EXP2_HW(-bs);
                bs = __builtin_fmaf(h * tos_t, e, bs) - h;
            }
        }
        b_out[o] = bs * LN2;
    }
}

// ---------------------------------------------------------------------------
// Kernel C: weight rows. XCD-partitioned segments (seg=bid&7), whole grid
// co-resident. DEPTH-4/6 PIPELINE (r22-proven optimum): entries fetched in
// uniform 16B pairs 3 pairs ahead; psp rows issued 2 iterations (4 entries)
// before use. r23/r24/r25 mapped the neighborhood: deeper pipelines,
// speculative prefetch, and uniform spike-entries all inflate FETCH (L2
// locality break) and regress. This structure is the measured Pareto point.
// ---------------------------------------------------------------------------
__global__ __launch_bounds__(256)
void stdp_main_kernel(const float* __restrict__ psp,
                      const float* __restrict__ w_in,
                      const uint2* __restrict__ lists,
                      const int* __restrict__ counts,
                      float* __restrict__ w_out) {
    const int bid  = blockIdx.x;
    const int seg  = bid & 7;
    const int wv   = __builtin_amdgcn_readfirstlane(threadIdx.x >> 6);
    const int lane = threadIdx.x & 63;
    const int o    = ((bid >> 3) << 2) | wv;
    const int lane4 = seg * 64 + lane;             // float4 index within the row

    const float4* __restrict__ psp4 = (const float4*)psp + lane4;
    float4 w0 = ((const float4*)w_in)[(size_t)o * I4 + lane4];
    float4 n = make_float4(w0.x * -LOG2E, w0.y * -LOG2E,
                           w0.z * -LOG2E, w0.w * -LOG2E);

    const uint2* lp = lists + (size_t)o * LSTRIDE; // uniform base
    const int count = counts[o];                   // uniform -> s_load

    auto rowof = [&](unsigned ex) -> float4 {
        return psp4[(size_t)(ex & 0x3FFFu) << 9];
    };

    if (count > 0) {
        // preload 3 entry-pairs (uniform 16B -> s_load_dwordx4) + 4 rows
        uint4 A = *(const uint4*)(lp + 0);         // E0,E1
        uint4 B = *(const uint4*)(lp + 2);         // E2,E3
        uint4 C = *(const uint4*)(lp + 4);         // E4,E5
        float4 p0 = rowof(A.x), p1 = rowof(A.z);
        float4 p2 = rowof(B.x), p3 = rowof(B.z);

        for (int k = 0; k < count; k += 2) {
            const uint4 D = *(const uint4*)(lp + k + 6);   // entries k+6,k+7
            const float4 p4 = rowof(C.x), p5 = rowof(C.z); // rows k+4,k+5

            // ---- update entry k (A.x/A.y, row p0) ----
            {
                float4 c = p0;
                unsigned rem = (A.x >> 18) & 0x3FFu;
                if (rem) {
                    unsigned t10 = (A.x & 0x3FFFu) - ((A.x >> 14) & 0xFu);
                    do {
                        int sbit = __ffs(rem) - 1;
                        rem &= rem - 1;
                        const float4 q = psp4[(size_t)(t10 + sbit) << 9];
                        c.x += q.x; c.y += q.y; c.z += q.z; c.w += q.w;
                    } while (rem);
                }
                const float ninv = __uint_as_float(A.y);
                const float tosf = (float)(A.x >> 28);
                float t, s;
                t = EXP2_HW(n.x); s = __builtin_fmaf(c.x, t, -tosf); n.x = __builtin_fmaf(ninv, s, n.x);
                t = EXP2_HW(n.y); s = __builtin_fmaf(c.y, t, -tosf); n.y = __builtin_fmaf(ninv, s, n.y);
                t = EXP2_HW(n.z); s = __builtin_fmaf(c.z, t, -tosf); n.z = __builtin_fmaf(ninv, s, n.z);
                t = EXP2_HW(n.w); s = __builtin_fmaf(c.w, t, -tosf); n.w = __builtin_fmaf(ninv, s, n.w);
            }
            // ---- update entry k+1 (A.z/A.w, row p1) ----
            {
                float4 c = p1;
                unsigned rem = (A.z >> 18) & 0x3FFu;
                if (rem) {
                    unsigned t10 = (A.z & 0x3FFFu) - ((A.z >> 14) & 0xFu);
                    do {
                        int sbit = __ffs(rem) - 1;
                        rem &= rem - 1;
                        const float4 q = psp4[(size_t)(t10 + sbit) << 9];
                        c.x += q.x; c.y += q.y; c.z += q.z; c.w += q.w;
                    } while (rem);
                }
                const float ninv = __uint_as_float(A.w);
                const float tosf = (float)(A.z >> 28);
                float t, s;
                t = EXP2_HW(n.x); s = __builtin_fmaf(c.x, t, -tosf); n.x = __builtin_fmaf(ninv, s, n.x);
                t = EXP2_HW(n.y); s = __builtin_fmaf(c.y, t, -tosf); n.y = __builtin_fmaf(ninv, s, n.y);
                t = EXP2_HW(n.z); s = __builtin_fmaf(c.z, t, -tosf); n.z = __builtin_fmaf(ninv, s, n.z);
                t = EXP2_HW(n.w); s = __builtin_fmaf(c.w, t, -tosf); n.w = __builtin_fmaf(ninv, s, n.w);
            }

            A = B; B = C; C = D;
            p0 = p2; p1 = p3; p2 = p4; p3 = p5;
        }
    }

    float4 ov = make_float4(n.x * -LN2, n.y * -LN2, n.z * -LN2, n.w * -LN2);
    ((float4*)w_out)[(size_t)o * I4 + lane4] = ov;
}

// ---------------------------------------------------------------------------
extern "C" void kernel_launch(void* const* d_in, const int* in_sizes, int n_in,
                              void* d_out, int out_size, void* d_ws, size_t ws_size,
                              hipStream_t stream) {
    const float* psp = (const float*)d_in[0];   // (T, I)
    const float* spk = (const float*)d_in[1];   // (T, O)
    const float* w   = (const float*)d_in[2];   // (O, I)
    const float* b   = (const float*)d_in[3];   // (O,)
    const float* Nk  = (const float*)d_in[4];   // (O, 1)

    float* w_out = (float*)d_out;
    float* b_out = (float*)d_out + (size_t)O_DIM * I_DIM;

    char* ws = (char*)d_ws;
    unsigned short* mask_T = (unsigned short*)ws;                              // 2 MB
    uint2*          lists  = (uint2*)(ws + (size_t)O_DIM * ITERS * 2);         // 2.75 MB
    int*            counts = (int*)(ws + (size_t)O_DIM * ITERS * 2
                                       + (size_t)O_DIM * LSTRIDE * 8);         // 4 KB
    float*          toss   = (float*)(counts + O_DIM);                         // 4 KB

    prep_kernel<<<ITERS, 256, 0, stream>>>(spk, mask_T, toss);
    compact_bias_kernel<<<260, 256, 0, stream>>>(mask_T, toss, Nk, b,
                                                 lists, counts, b_out);
    stdp_main_kernel<<<O_DIM / 4 * 8, 256, 0, stream>>>(psp, w, lists, counts, w_out);
}